// Round 2
// baseline (210.321 us; speedup 1.0000x reference)
//
#include <hip/hip_runtime.h>
#include <hip/hip_bf16.h>

// EdgeDegreeEmbeddingNetwork: N=10000 atoms, K=32 neighbors, NB=64, C=128, L=3, H=64
// out (N,9,128) f32 = concat_l [ sh_l^T @ (masked MLP_l(concat[scalars,tgt,src])) ] / 10

typedef __attribute__((ext_vector_type(8))) short bf16x8;   // 8 bf16 in 4 VGPRs
typedef __attribute__((ext_vector_type(4))) float f32x4;

__device__ __forceinline__ unsigned short f2bf(float f) {
  __hip_bfloat16 h = __float2bfloat16(f);
  return *reinterpret_cast<unsigned short*>(&h);
}
__device__ __forceinline__ float bf2f(unsigned short u) {
  __hip_bfloat16 h;
  *reinterpret_cast<unsigned short*>(&h) = u;
  return __bfloat162float(h);
}

// ---------------- weight repack: f32 -> bf16 MFMA B-fragment order ----------------
// ws layout (ushort elements):
//   W1F: [l:3][Nt:4][Ks:6][512]   offset 0      (36864)
//   W2F: [l:3][Nt:4][Ks:2][512]   offset 36864  (12288)
//   W3F: [l:3][Nt:8][Ks:2][512]   offset 49152  (24576)   total 73728 ushort
//   mask-dtype flag: ((int*)ws)[36864]  (byte offset 147456)
// frag element e = lane*8 + j  <->  W[k = Ks*32 + (lane>>4)*8 + j][n = Nt*16 + (lane&15)]
__global__ __launch_bounds__(256) void prep_weights(
    const float* __restrict__ W1, const float* __restrict__ W2,
    const float* __restrict__ W3, unsigned short* __restrict__ wf) {
  int idx = blockIdx.x * 256 + threadIdx.x;
  if (idx >= 73728) return;
  float val;
  if (idx < 36864) {                       // W1: 192 x 64
    int l = idx / 12288, r = idx % 12288;
    int blk = r >> 9, e = r & 511;
    int Nt = blk / 6, Ks = blk % 6;
    int lane = e >> 3, j = e & 7;
    int k = Ks * 32 + (lane >> 4) * 8 + j;
    int nn = Nt * 16 + (lane & 15);
    val = W1[l * 192 * 64 + k * 64 + nn];
  } else if (idx < 49152) {                // W2: 64 x 64
    int t = idx - 36864;
    int l = t / 4096, r = t % 4096;
    int blk = r >> 9, e = r & 511;
    int Nt = blk >> 1, Ks = blk & 1;
    int lane = e >> 3, j = e & 7;
    int k = Ks * 32 + (lane >> 4) * 8 + j;
    int nn = Nt * 16 + (lane & 15);
    val = W2[l * 64 * 64 + k * 64 + nn];
  } else {                                 // W3: 64 x 128
    int t = idx - 49152;
    int l = t / 8192, r = t % 8192;
    int blk = r >> 9, e = r & 511;
    int Nt = blk >> 1, Ks = blk & 1;
    int lane = e >> 3, j = e & 7;
    int k = Ks * 32 + (lane >> 4) * 8 + j;
    int nn = Nt * 16 + (lane & 15);
    val = W3[l * 64 * 128 + k * 128 + nn];
  }
  wf[idx] = f2bf(val);
}

// ---------------- mask dtype sniffer: 0=int32, 1=bytes(bool/int8), 2=float32 ------
__global__ __launch_bounds__(256) void sniff_mask(const unsigned int* __restrict__ m,
                                                  int* __restrict__ flag) {
  __shared__ int cOther, cFloat;
  if (threadIdx.x == 0) { cOther = 0; cFloat = 0; }
  __syncthreads();
  int other = 0, flt = 0;
#pragma unroll
  for (int i = 0; i < 8; ++i) {
    unsigned int w = m[threadIdx.x * 8 + i];
    if (w == 0x3F800000u) flt++;
    else if (w > 1u) other++;
  }
  if (other) atomicAdd(&cOther, other);
  if (flt)   atomicAdd(&cFloat, flt);
  __syncthreads();
  if (threadIdx.x == 0) {
    int f;
    if (cOther == 0 && cFloat == 0) f = 0;        // all words {0,1}: int32
    else if (cFloat > cOther)       f = 2;        // float32 1.0f pattern
    else                            f = 1;        // packed bytes
    *flag = f;
  }
}

// ---------------- LN + silu phase: Hf(f32, +bias) -> LN -> silu -> Hb(bf16) -------
__device__ __forceinline__ void ln_silu_phase(
    const float* Hf, unsigned short* Hb,
    const float* __restrict__ bb, const float* __restrict__ gg,
    const float* __restrict__ be, int tid) {
  int e = tid >> 3, c0 = (tid & 7) * 8;     // 8 threads per edge row, 8 ch each
  float v[8]; float s = 0.f, s2 = 0.f;
#pragma unroll
  for (int j = 0; j < 8; ++j) {
    float x = Hf[e * 68 + c0 + j] + bb[c0 + j];
    v[j] = x; s += x; s2 += x * x;
  }
#pragma unroll
  for (int m = 1; m < 8; m <<= 1) {         // 8 contiguous lanes per edge
    s  += __shfl_xor(s, m);
    s2 += __shfl_xor(s2, m);
  }
  float mu  = s * 0.015625f;
  float var = s2 * 0.015625f - mu * mu;
  float rstd = rsqrtf(var + 1e-5f);
#pragma unroll
  for (int j = 0; j < 8; ++j) {
    float y = (v[j] - mu) * rstd * gg[c0 + j] + be[c0 + j];
    float sl = y * (1.0f / (1.0f + __expf(-y)));
    Hb[e * 72 + c0 + j] = f2bf(sl);
  }
}

// ---------------- main kernel: one block (256 thr / 4 waves) per atom -------------
__global__ __launch_bounds__(256) void edge_net_kernel(
    const int*   __restrict__ atomic_numbers,
    const float* __restrict__ edge_vec,
    const int*   __restrict__ f_idx,
    const void*  __restrict__ attn_mask,
    const float* __restrict__ edge_scalars,
    const float* __restrict__ src_emb,
    const float* __restrict__ tgt_emb,
    const float* __restrict__ b1, const float* __restrict__ g1, const float* __restrict__ be1,
    const float* __restrict__ b2, const float* __restrict__ g2, const float* __restrict__ be2,
    const float* __restrict__ b3,
    const unsigned short* __restrict__ wf,
    const int* __restrict__ mask_flag,
    float* __restrict__ out) {

  __shared__ __align__(16) unsigned short Xlds[32 * 200];  // 32 x 192 bf16, pad->200
  __shared__ float          Hf[32 * 68];                   // raw layer out, f32
  __shared__ __align__(16) unsigned short Hb[32 * 72];     // activated, bf16, pad->72
  __shared__ float          H3[32 * 132];                  // layer3 out, f32, pad->132
  __shared__ float sh_lds[32 * 12];                        // 9 sh values per edge
  __shared__ float tgt_lds[64];
  __shared__ float maskf[32];
  __shared__ int   srcAn[32];

  const int tid  = threadIdx.x;
  const int n    = blockIdx.x;
  const int wave = tid >> 6;
  const int lane = tid & 63;

  // ---- phase 0: gathers, sh, mask ----
  const int an = atomic_numbers[n];
  if (tid < 64) tgt_lds[tid] = tgt_emb[an * 64 + tid];
  if (tid < 32) {
    int src_node = f_idx[n * 32 + tid];
    srcAn[tid] = atomic_numbers[src_node];
    int mflag = *mask_flag;
    bool masked;
    if (mflag == 0)
      masked = ((const int*)attn_mask)[n * 32 + tid] != 0;
    else if (mflag == 1)
      masked = ((const unsigned char*)attn_mask)[n * 32 + tid] != 0;
    else
      masked = ((const float*)attn_mask)[n * 32 + tid] != 0.0f;
    maskf[tid] = masked ? 0.0f : 1.0f;
  }
  if (tid >= 64 && tid < 96) {
    int k = tid - 64;
    const float* ev = edge_vec + (size_t)(n * 32 + k) * 3;
    float ex = ev[0], ey = ev[1], ez = ev[2];
    float rn = rsqrtf(ex * ex + ey * ey + ez * ez);
    float x = ex * rn, y = ey * rn, z = ez * rn;
    const float s3 = 1.7320508075688772f;
    float* srow = &sh_lds[k * 12];
    srow[0] = 1.0f;                       // l=0
    srow[1] = y; srow[2] = z; srow[3] = x;// l=1: [y,z,x]
    srow[4] = s3 * x * y;
    srow[5] = s3 * y * z;
    srow[6] = 1.5f * z * z - 0.5f;
    srow[7] = s3 * x * z;
    srow[8] = 0.5f * s3 * (x * x - y * y);
  }
  __syncthreads();

  // ---- build X = [edge_scalars | tgt | src] (32 x 192, bf16) ----
  {
    int k = tid >> 3;
    int c0 = (tid & 7) * 8;
    unsigned short* xr = &Xlds[k * 200];
    const float4* es = reinterpret_cast<const float4*>(
        edge_scalars + (size_t)(n * 32 + k) * 64 + c0);
    float4 e0 = es[0], e1 = es[1];
    xr[c0 + 0] = f2bf(e0.x); xr[c0 + 1] = f2bf(e0.y);
    xr[c0 + 2] = f2bf(e0.z); xr[c0 + 3] = f2bf(e0.w);
    xr[c0 + 4] = f2bf(e1.x); xr[c0 + 5] = f2bf(e1.y);
    xr[c0 + 6] = f2bf(e1.z); xr[c0 + 7] = f2bf(e1.w);
#pragma unroll
    for (int j = 0; j < 8; ++j) xr[64 + c0 + j] = f2bf(tgt_lds[c0 + j]);
    const float4* sp = reinterpret_cast<const float4*>(
        src_emb + (size_t)srcAn[k] * 64 + c0);
    float4 s0 = sp[0], s1 = sp[1];
    xr[128 + c0 + 0] = f2bf(s0.x); xr[128 + c0 + 1] = f2bf(s0.y);
    xr[128 + c0 + 2] = f2bf(s0.z); xr[128 + c0 + 3] = f2bf(s0.w);
    xr[128 + c0 + 4] = f2bf(s1.x); xr[128 + c0 + 5] = f2bf(s1.y);
    xr[128 + c0 + 6] = f2bf(s1.z); xr[128 + c0 + 7] = f2bf(s1.w);
  }
  __syncthreads();

  const int lrow = lane & 15;          // A-frag row within M-tile
  const int kgrp = (lane >> 4) * 8;    // A/B-frag k-offset within K=32 step

  for (int l = 0; l < 3; ++l) {
    const unsigned short* w1f = wf + l * 12288;
    const unsigned short* w2f = wf + 36864 + l * 4096;
    const unsigned short* w3f = wf + 49152 + l * 8192;

    // ---- layer 1: X(32x192) @ W1(192x64); wave w owns N-tile w ----
    {
      f32x4 acc0 = {0.f, 0.f, 0.f, 0.f}, acc1 = {0.f, 0.f, 0.f, 0.f};
#pragma unroll
      for (int ks = 0; ks < 6; ++ks) {
        bf16x8 b = *reinterpret_cast<const bf16x8*>(
            w1f + ((wave * 6 + ks) << 9) + lane * 8);
        int kb = ks * 32 + kgrp;
        bf16x8 a0 = *reinterpret_cast<const bf16x8*>(&Xlds[lrow * 200 + kb]);
        bf16x8 a1 = *reinterpret_cast<const bf16x8*>(&Xlds[(lrow + 16) * 200 + kb]);
        acc0 = __builtin_amdgcn_mfma_f32_16x16x32_bf16(a0, b, acc0, 0, 0, 0);
        acc1 = __builtin_amdgcn_mfma_f32_16x16x32_bf16(a1, b, acc1, 0, 0, 0);
      }
      int dr = (lane >> 4) * 4;
      int dc = wave * 16 + (lane & 15);
#pragma unroll
      for (int i = 0; i < 4; ++i) {
        Hf[(dr + i) * 68 + dc]      = acc0[i];
        Hf[(dr + i + 16) * 68 + dc] = acc1[i];
      }
    }
    __syncthreads();
    ln_silu_phase(Hf, Hb, b1 + l * 64, g1 + l * 64, be1 + l * 64, tid);
    __syncthreads();

    // ---- layer 2: Hb(32x64) @ W2(64x64) ----
    {
      f32x4 acc0 = {0.f, 0.f, 0.f, 0.f}, acc1 = {0.f, 0.f, 0.f, 0.f};
#pragma unroll
      for (int ks = 0; ks < 2; ++ks) {
        bf16x8 b = *reinterpret_cast<const bf16x8*>(
            w2f + ((wave * 2 + ks) << 9) + lane * 8);
        int kb = ks * 32 + kgrp;
        bf16x8 a0 = *reinterpret_cast<const bf16x8*>(&Hb[lrow * 72 + kb]);
        bf16x8 a1 = *reinterpret_cast<const bf16x8*>(&Hb[(lrow + 16) * 72 + kb]);
        acc0 = __builtin_amdgcn_mfma_f32_16x16x32_bf16(a0, b, acc0, 0, 0, 0);
        acc1 = __builtin_amdgcn_mfma_f32_16x16x32_bf16(a1, b, acc1, 0, 0, 0);
      }
      int dr = (lane >> 4) * 4;
      int dc = wave * 16 + (lane & 15);
#pragma unroll
      for (int i = 0; i < 4; ++i) {
        Hf[(dr + i) * 68 + dc]      = acc0[i];
        Hf[(dr + i + 16) * 68 + dc] = acc1[i];
      }
    }
    __syncthreads();
    ln_silu_phase(Hf, Hb, b2 + l * 64, g2 + l * 64, be2 + l * 64, tid);
    __syncthreads();

    // ---- layer 3: Hb(32x64) @ W3(64x128), +b3, mask -> H3 f32 ----
    {
      f32x4 acc[2][2] = {{{0.f,0.f,0.f,0.f},{0.f,0.f,0.f,0.f}},
                         {{0.f,0.f,0.f,0.f},{0.f,0.f,0.f,0.f}}};
#pragma unroll
      for (int ks = 0; ks < 2; ++ks) {
        int kb = ks * 32 + kgrp;
        bf16x8 a0 = *reinterpret_cast<const bf16x8*>(&Hb[lrow * 72 + kb]);
        bf16x8 a1 = *reinterpret_cast<const bf16x8*>(&Hb[(lrow + 16) * 72 + kb]);
#pragma unroll
        for (int h = 0; h < 2; ++h) {
          int nt = wave + 4 * h;
          bf16x8 b = *reinterpret_cast<const bf16x8*>(
              w3f + ((nt * 2 + ks) << 9) + lane * 8);
          acc[h][0] = __builtin_amdgcn_mfma_f32_16x16x32_bf16(a0, b, acc[h][0], 0, 0, 0);
          acc[h][1] = __builtin_amdgcn_mfma_f32_16x16x32_bf16(a1, b, acc[h][1], 0, 0, 0);
        }
      }
      const float* b3l = b3 + l * 128;
      int dr = (lane >> 4) * 4;
#pragma unroll
      for (int h = 0; h < 2; ++h) {
        int ch = (wave + 4 * h) * 16 + (lane & 15);
        float bias = b3l[ch];
#pragma unroll
        for (int i = 0; i < 4; ++i) {
          int r = dr + i;
          H3[r * 132 + ch]        = (acc[h][0][i] + bias) * maskf[r];
          H3[(r + 16) * 132 + ch] = (acc[h][1][i] + bias) * maskf[r + 16];
        }
      }
    }
    __syncthreads();

    // ---- einsum: out[l*l + d][c] = 0.1 * sum_k sh[k][l*l+d] * H3[k][c] ----
    {
      int c  = tid & 127;
      int hh = tid >> 7;
      int dcount = 2 * l + 1, base = l * l;
      for (int d = hh; d < dcount; d += 2) {
        float accv = 0.f;
#pragma unroll
        for (int k2 = 0; k2 < 32; ++k2)
          accv += sh_lds[k2 * 12 + base + d] * H3[k2 * 132 + c];
        out[((size_t)n * 9 + base + d) * 128 + c] = 0.1f * accv;
      }
    }
    __syncthreads();
  }
}

extern "C" void kernel_launch(void* const* d_in, const int* in_sizes, int n_in,
                              void* d_out, int out_size, void* d_ws, size_t ws_size,
                              hipStream_t stream) {
  const int*   atomic_numbers = (const int*)  d_in[0];
  const float* edge_vec       = (const float*)d_in[1];
  const int*   f_idx          = (const int*)  d_in[2];
  const void*  attn_mask      = d_in[3];
  const float* edge_scalars   = (const float*)d_in[4];
  const float* src_emb        = (const float*)d_in[5];
  const float* tgt_emb        = (const float*)d_in[6];
  const float* W1  = (const float*)d_in[7];
  const float* b1  = (const float*)d_in[8];
  const float* g1  = (const float*)d_in[9];
  const float* be1 = (const float*)d_in[10];
  const float* W2  = (const float*)d_in[11];
  const float* b2  = (const float*)d_in[12];
  const float* g2  = (const float*)d_in[13];
  const float* be2 = (const float*)d_in[14];
  const float* W3  = (const float*)d_in[15];
  const float* b3  = (const float*)d_in[16];

  unsigned short* wf = (unsigned short*)d_ws;
  int* mask_flag = ((int*)d_ws) + 36864;        // byte offset 147456
  float* out = (float*)d_out;
  const int N = in_sizes[0];

  prep_weights<<<288, 256, 0, stream>>>(W1, W2, W3, wf);
  sniff_mask<<<1, 256, 0, stream>>>((const unsigned int*)attn_mask, mask_flag);
  edge_net_kernel<<<N, 256, 0, stream>>>(
      atomic_numbers, edge_vec, f_idx, attn_mask, edge_scalars,
      src_emb, tgt_emb, b1, g1, be1, b2, g2, be2, b3, wf, mask_flag, out);
}

// Round 3
// 185.318 us; speedup vs baseline: 1.1349x; 1.1349x over previous
//
#include <hip/hip_runtime.h>
#include <hip/hip_bf16.h>

// EdgeDegreeEmbeddingNetwork: N=10000 atoms, K=32 neighbors, NB=64, C=128, L=3, H=64
// out (N,9,128) f32 = concat_l [ (sh_l*mask)^T @ MLP_l(concat[scalars,tgt,src]) ] / 10
//
// Structure: 2 atoms/block, 4 waves. Wave (a,h) owns 16 edges of atom a.
// All layers computed as H^T = W^T @ X^T so each wave holds full channel dim:
// LN/silu fully in registers; inter-layer exchange via wave-private LDS (no bars).
// Einsum = MFMA with A=sh^T*mask (bf16), B=H3^T. 2 __syncthreads per l.

typedef __attribute__((ext_vector_type(8))) short bf16x8;   // 8 bf16 / 4 VGPR
typedef __attribute__((ext_vector_type(4))) short bf16x4;
typedef __attribute__((ext_vector_type(4))) float f32x4;

__device__ __forceinline__ unsigned short f2bf(float f) {
  __hip_bfloat16 h = __float2bfloat16(f);
  return *reinterpret_cast<unsigned short*>(&h);
}

// ---------------- weight repack: f32 -> bf16 MFMA A-fragment order ----------------
// frag element e=lane*8+j <-> W[k = Ks*32 + (lane>>4)*8 + j][n = Nt*16 + (lane&15)]
// (same map as a B-frag of W, so it serves as A-frag of W^T: A[ch][feat]=W[feat][ch])
// ws layout (ushort): W1F [l:3][4][6][512] @0 ; W2F [l:3][4][2][512] @36864 ;
//                     W3F [l:3][8][2][512] @49152 ; mask flag @ int offset 36864
__global__ __launch_bounds__(256) void prep_weights(
    const float* __restrict__ W1, const float* __restrict__ W2,
    const float* __restrict__ W3, unsigned short* __restrict__ wf) {
  int idx = blockIdx.x * 256 + threadIdx.x;
  if (idx >= 73728) return;
  float val;
  if (idx < 36864) {                       // W1: 192 x 64
    int l = idx / 12288, r = idx % 12288;
    int blk = r >> 9, e = r & 511;
    int Nt = blk / 6, Ks = blk % 6;
    int lane = e >> 3, j = e & 7;
    int k = Ks * 32 + (lane >> 4) * 8 + j;
    int nn = Nt * 16 + (lane & 15);
    val = W1[l * 192 * 64 + k * 64 + nn];
  } else if (idx < 49152) {                // W2: 64 x 64
    int t = idx - 36864;
    int l = t / 4096, r = t % 4096;
    int blk = r >> 9, e = r & 511;
    int Nt = blk >> 1, Ks = blk & 1;
    int lane = e >> 3, j = e & 7;
    int k = Ks * 32 + (lane >> 4) * 8 + j;
    int nn = Nt * 16 + (lane & 15);
    val = W2[l * 64 * 64 + k * 64 + nn];
  } else {                                 // W3: 64 x 128
    int t = idx - 49152;
    int l = t / 8192, r = t % 8192;
    int blk = r >> 9, e = r & 511;
    int Nt = blk >> 1, Ks = blk & 1;
    int lane = e >> 3, j = e & 7;
    int k = Ks * 32 + (lane >> 4) * 8 + j;
    int nn = Nt * 16 + (lane & 15);
    val = W3[l * 64 * 128 + k * 128 + nn];
  }
  wf[idx] = f2bf(val);
}

// ---------------- mask dtype sniffer: 0=int32, 1=bytes, 2=float32 ----------------
__global__ __launch_bounds__(256) void sniff_mask(const unsigned int* __restrict__ m,
                                                  int* __restrict__ flag) {
  __shared__ int cOther, cFloat;
  if (threadIdx.x == 0) { cOther = 0; cFloat = 0; }
  __syncthreads();
  int other = 0, flt = 0;
#pragma unroll
  for (int i = 0; i < 8; ++i) {
    unsigned int w = m[threadIdx.x * 8 + i];
    if (w == 0x3F800000u) flt++;
    else if (w > 1u) other++;
  }
  if (other) atomicAdd(&cOther, other);
  if (flt)   atomicAdd(&cFloat, flt);
  __syncthreads();
  if (threadIdx.x == 0) {
    int f;
    if (cOther == 0 && cFloat == 0) f = 0;
    else if (cFloat > cOther)       f = 2;
    else                            f = 1;
    *flag = f;
  }
}

__device__ __forceinline__ bf16x8 cvt8(float4 a, float4 b) {
  bf16x8 r;
  r[0] = (short)f2bf(a.x); r[1] = (short)f2bf(a.y);
  r[2] = (short)f2bf(a.z); r[3] = (short)f2bf(a.w);
  r[4] = (short)f2bf(b.x); r[5] = (short)f2bf(b.y);
  r[6] = (short)f2bf(b.z); r[7] = (short)f2bf(b.w);
  return r;
}

// In-register LN(+bias) + silu over 64 channels of one edge, spread across the
// 4 lanes {e, e+16, e+32, e+48}; writes bf16 to wave-private Hb[e][ch] (pad 72).
__device__ __forceinline__ void ln_silu_reg(
    const f32x4* acc, const float* __restrict__ bb, const float* __restrict__ gg,
    const float* __restrict__ be, unsigned short* HbW, int e, int g) {
  float v[16]; float s = 0.f, s2 = 0.f;
#pragma unroll
  for (int mt = 0; mt < 4; ++mt) {
    float4 b4 = *reinterpret_cast<const float4*>(bb + mt * 16 + 4 * g);
    const float* b4p = reinterpret_cast<const float*>(&b4);
#pragma unroll
    for (int i = 0; i < 4; ++i) {
      float x = acc[mt][i] + b4p[i];
      v[mt * 4 + i] = x; s += x; s2 += x * x;
    }
  }
  s  += __shfl_xor(s, 16);  s2 += __shfl_xor(s2, 16);
  s  += __shfl_xor(s, 32);  s2 += __shfl_xor(s2, 32);
  float mu  = s * 0.015625f;
  float var = s2 * 0.015625f - mu * mu;
  float rstd = rsqrtf(var + 1e-5f);
#pragma unroll
  for (int mt = 0; mt < 4; ++mt) {
    float4 g4 = *reinterpret_cast<const float4*>(gg + mt * 16 + 4 * g);
    float4 e4 = *reinterpret_cast<const float4*>(be + mt * 16 + 4 * g);
    const float* g4p = reinterpret_cast<const float*>(&g4);
    const float* e4p = reinterpret_cast<const float*>(&e4);
    bf16x4 pk;
#pragma unroll
    for (int i = 0; i < 4; ++i) {
      float y  = (v[mt * 4 + i] - mu) * rstd * g4p[i] + e4p[i];
      float sl = y * (1.0f / (1.0f + __expf(-y)));
      pk[i] = (short)f2bf(sl);
    }
    *reinterpret_cast<bf16x4*>(HbW + e * 72 + mt * 16 + 4 * g) = pk;  // b64 write
  }
}

#define MFMA __builtin_amdgcn_mfma_f32_16x16x32_bf16

__global__ __launch_bounds__(256, 4) void edge_net_kernel(
    const int*   __restrict__ an_arr,
    const float* __restrict__ edge_vec,
    const int*   __restrict__ f_idx,
    const void*  __restrict__ attn_mask,
    const float* __restrict__ edge_scalars,
    const float* __restrict__ src_emb,
    const float* __restrict__ tgt_emb,
    const float* __restrict__ b1, const float* __restrict__ g1, const float* __restrict__ be1,
    const float* __restrict__ b2, const float* __restrict__ g2, const float* __restrict__ be2,
    const float* __restrict__ b3,
    const unsigned short* __restrict__ wf,
    const int* __restrict__ mask_flag,
    float* __restrict__ out, int Nat) {

  __shared__ __align__(16) unsigned short Hb[4][16 * 72];    // wave-private, 9.2 KB
  __shared__ __align__(16) unsigned short H3T[2][128 * 40];  // [atom][ch][k] 20.5 KB
  __shared__ __align__(16) unsigned short shT[2][16 * 40];   // [atom][d][k]  2.5 KB

  const int tid  = threadIdx.x;
  const int wave = tid >> 6, lane = tid & 63;
  const int e = lane & 15, g = lane >> 4;
  const int a = wave >> 1, h = wave & 1;
  int n = blockIdx.x * 2 + a;
  const bool valid = (n < Nat);
  if (!valid) n = Nat - 1;
  const int k = h * 16 + e;

  // ---- phase 0: per-lane gathers, sh*mask -> shT, X -> 24 VGPRs ----
  const int an   = an_arr[n];
  const int srcA = an_arr[f_idx[n * 32 + k]];
  const int mflag = *mask_flag;
  bool masked;
  if (mflag == 0)      masked = ((const int*)attn_mask)[n * 32 + k] != 0;
  else if (mflag == 1) masked = ((const unsigned char*)attn_mask)[n * 32 + k] != 0;
  else                 masked = ((const float*)attn_mask)[n * 32 + k] != 0.0f;
  const float mf = masked ? 0.0f : 1.0f;

  {
    const float* ev = edge_vec + ((size_t)n * 32 + k) * 3;
    float ex = ev[0], ey = ev[1], ez = ev[2];
    float rn = rsqrtf(ex * ex + ey * ey + ez * ez);
    float x = ex * rn, y = ey * rn, z = ez * rn;
    const float s3 = 1.7320508075688772f;
    float s[9];
    s[0] = 1.f; s[1] = y; s[2] = z; s[3] = x;
    s[4] = s3 * x * y; s[5] = s3 * y * z; s[6] = 1.5f * z * z - 0.5f;
    s[7] = s3 * x * z; s[8] = 0.5f * s3 * (x * x - y * y);
    if (g < 3) {
#pragma unroll
      for (int q = 0; q < 3; ++q)
        shT[a][(g * 3 + q) * 40 + k] = f2bf(s[g * 3 + q] * mf);
    }
  }

  bf16x8 xf[6];   // X^T B-frags: lane(e,g) holds feats {ks*32 + g*8 + j} of edge k
  {
    const float* es = edge_scalars + ((size_t)n * 32 + k) * 64 + g * 8;
    const float4* p0 = reinterpret_cast<const float4*>(es);
    const float4* p1 = reinterpret_cast<const float4*>(es + 32);
    xf[0] = cvt8(p0[0], p0[1]);
    xf[1] = cvt8(p1[0], p1[1]);
    const float4* t0 = reinterpret_cast<const float4*>(tgt_emb + an * 64 + g * 8);
    const float4* t1 = reinterpret_cast<const float4*>(tgt_emb + an * 64 + 32 + g * 8);
    xf[2] = cvt8(t0[0], t0[1]);
    xf[3] = cvt8(t1[0], t1[1]);
    const float4* s0 = reinterpret_cast<const float4*>(src_emb + (size_t)srcA * 64 + g * 8);
    const float4* s1 = reinterpret_cast<const float4*>(src_emb + (size_t)srcA * 64 + 32 + g * 8);
    xf[4] = cvt8(s0[0], s0[1]);
    xf[5] = cvt8(s1[0], s1[1]);
  }

  unsigned short* HbW = &Hb[wave][0];

  for (int l = 0; l < 3; ++l) {
    const unsigned short* w1a = wf + l * 12288;
    const unsigned short* w2a = wf + 36864 + l * 4096;
    const unsigned short* w3a = wf + 49152 + l * 8192;

    __syncthreads();   // previous einsum reads of H3T done before we rewrite it

    // ---- L1: H1^T(64x16/wave) = W1^T @ X^T, K=192 ----
    f32x4 acc1[4];
#pragma unroll
    for (int mt = 0; mt < 4; ++mt) acc1[mt] = (f32x4){0.f, 0.f, 0.f, 0.f};
#pragma unroll
    for (int mt = 0; mt < 4; ++mt)
#pragma unroll
      for (int ks = 0; ks < 6; ++ks) {
        bf16x8 wfr = *reinterpret_cast<const bf16x8*>(w1a + ((mt * 6 + ks) << 9) + lane * 8);
        acc1[mt] = MFMA(wfr, xf[ks], acc1[mt], 0, 0, 0);
      }
    ln_silu_reg(acc1, b1 + l * 64, g1 + l * 64, be1 + l * 64, HbW, e, g);
    asm volatile("s_waitcnt lgkmcnt(0)" ::: "memory");
    __builtin_amdgcn_sched_barrier(0);

    // ---- L2: K=64 ----
    bf16x8 hf[2];
#pragma unroll
    for (int ks = 0; ks < 2; ++ks)
      hf[ks] = *reinterpret_cast<const bf16x8*>(HbW + e * 72 + ks * 32 + g * 8);
    f32x4 acc2[4];
#pragma unroll
    for (int mt = 0; mt < 4; ++mt) acc2[mt] = (f32x4){0.f, 0.f, 0.f, 0.f};
#pragma unroll
    for (int mt = 0; mt < 4; ++mt)
#pragma unroll
      for (int ks = 0; ks < 2; ++ks) {
        bf16x8 wfr = *reinterpret_cast<const bf16x8*>(w2a + ((mt * 2 + ks) << 9) + lane * 8);
        acc2[mt] = MFMA(wfr, hf[ks], acc2[mt], 0, 0, 0);
      }
    ln_silu_reg(acc2, b2 + l * 64, g2 + l * 64, be2 + l * 64, HbW, e, g);
    asm volatile("s_waitcnt lgkmcnt(0)" ::: "memory");
    __builtin_amdgcn_sched_barrier(0);

    // ---- L3: H3^T(128x16/wave) = W3^T @ H2^T, K=64; +bias -> H3T LDS ----
#pragma unroll
    for (int ks = 0; ks < 2; ++ks)
      hf[ks] = *reinterpret_cast<const bf16x8*>(HbW + e * 72 + ks * 32 + g * 8);
    f32x4 acc3[8];
#pragma unroll
    for (int mt = 0; mt < 8; ++mt) acc3[mt] = (f32x4){0.f, 0.f, 0.f, 0.f};
#pragma unroll
    for (int mt = 0; mt < 8; ++mt)
#pragma unroll
      for (int ks = 0; ks < 2; ++ks) {
        bf16x8 wfr = *reinterpret_cast<const bf16x8*>(w3a + ((mt * 2 + ks) << 9) + lane * 8);
        acc3[mt] = MFMA(wfr, hf[ks], acc3[mt], 0, 0, 0);
      }
#pragma unroll
    for (int mt = 0; mt < 8; ++mt) {
      float4 bb = *reinterpret_cast<const float4*>(b3 + l * 128 + mt * 16 + 4 * g);
      const float* bbp = reinterpret_cast<const float*>(&bb);
#pragma unroll
      for (int i = 0; i < 4; ++i)
        H3T[a][(mt * 16 + 4 * g + i) * 40 + k] = f2bf(acc3[mt][i] + bbp[i]);
    }
    __syncthreads();   // H3T complete across the atom's two waves

    // ---- einsum: D(16x128) = shT(A) @ H3T(B); store rows l^2 .. l^2+2l ----
    bf16x8 af = *reinterpret_cast<const bf16x8*>(&shT[a][(lane & 15) * 40 + g * 8]);
    const int lo = l * l, hi = l * l + 2 * l;
#pragma unroll
    for (int nt = 0; nt < 4; ++nt) {
      bf16x8 bfr = *reinterpret_cast<const bf16x8*>(
          &H3T[a][(h * 64 + nt * 16 + (lane & 15)) * 40 + g * 8]);
      f32x4 ez = (f32x4){0.f, 0.f, 0.f, 0.f};
      ez = MFMA(af, bfr, ez, 0, 0, 0);
#pragma unroll
      for (int i = 0; i < 4; ++i) {
        int d = 4 * g + i;
        if (valid && d >= lo && d <= hi)
          out[((size_t)n * 9 + d) * 128 + h * 64 + nt * 16 + (lane & 15)] = 0.1f * ez[i];
      }
    }
  }
}

extern "C" void kernel_launch(void* const* d_in, const int* in_sizes, int n_in,
                              void* d_out, int out_size, void* d_ws, size_t ws_size,
                              hipStream_t stream) {
  const int*   atomic_numbers = (const int*)  d_in[0];
  const float* edge_vec       = (const float*)d_in[1];
  const int*   f_idx          = (const int*)  d_in[2];
  const void*  attn_mask      = d_in[3];
  const float* edge_scalars   = (const float*)d_in[4];
  const float* src_emb        = (const float*)d_in[5];
  const float* tgt_emb        = (const float*)d_in[6];
  const float* W1  = (const float*)d_in[7];
  const float* b1  = (const float*)d_in[8];
  const float* g1  = (const float*)d_in[9];
  const float* be1 = (const float*)d_in[10];
  const float* W2  = (const float*)d_in[11];
  const float* b2  = (const float*)d_in[12];
  const float* g2  = (const float*)d_in[13];
  const float* be2 = (const float*)d_in[14];
  const float* W3  = (const float*)d_in[15];
  const float* b3  = (const float*)d_in[16];

  unsigned short* wf = (unsigned short*)d_ws;
  int* mask_flag = ((int*)d_ws) + 36864;        // byte offset 147456
  float* out = (float*)d_out;
  const int N = in_sizes[0];

  prep_weights<<<288, 256, 0, stream>>>(W1, W2, W3, wf);
  sniff_mask<<<1, 256, 0, stream>>>((const unsigned int*)attn_mask, mask_flag);
  edge_net_kernel<<<(N + 1) / 2, 256, 0, stream>>>(
      atomic_numbers, edge_vec, f_idx, attn_mask, edge_scalars,
      src_emb, tgt_emb, b1, g1, be1, b2, g2, be2, b3, wf, mask_flag, out, N);
}